// Round 1
// baseline (320.658 us; speedup 1.0000x reference)
//
#include <hip/hip_runtime.h>
#include <float.h>

// RankLoss: per-row softmax stats (max1+idx, max2, Z, exp(x[t]-max1)) suffice.
// One wave (64 lanes) per row -> no LDS, no __syncthreads in the main kernel.
// Memory-bound: 327.7 MB fp32 streamed once, coalesced float4 loads.

constexpr int B      = 32768;
constexpr int C_ENT  = 1000;   // 250 float4
constexpr int C_REL  = 500;    // 125 float4

// Online-softmax + top2 + argmax combine.
// State: m1 (running max), i1 (its index, lowest on tie), m2 (second max),
//        Z (sum of exp(x - m1) over the lane subset).
__device__ inline void combine_stats(float& m1, int& i1, float& m2, float& Z,
                                     float bm1, int bi1, float bm2, float bZ) {
  bool bwin = (bm1 > m1) || (bm1 == m1 && bi1 < i1);
  float wm1 = bwin ? bm1 : m1;
  int   wi1 = bwin ? bi1 : i1;
  float wm2 = bwin ? bm2 : m2;
  float lm1 = bwin ? m1  : bm1;   // loser's top1
  float wZ  = bwin ? bZ  : Z;
  float lZ  = bwin ? Z   : bZ;
  m1 = wm1;
  i1 = wi1;
  m2 = fmaxf(wm2, lm1);           // loser.m2 <= loser.m1, so this is exact
  // lm1 - wm1 <= 0; with -FLT_MAX sentinels: exp(-huge)=0 (lZ=0 anyway),
  // both-sentinel case gives exp(0)*0 = 0. No NaN (sentinel is finite).
  Z  = wZ + lZ * __expf(lm1 - wm1);
}

// NK: float4 loads per lane; C4: row length in float4s.
template<int NK, int C4>
__device__ inline void row_stats(const float* __restrict__ row, int lane, int target,
                                 float& p_top1, float& p_top2, int& amax, float& p_tgt) {
  const float4* row4 = (const float4*)row;
  float4 v[NK];
#pragma unroll
  for (int k = 0; k < NK; ++k) {
    int idx = lane + 64 * k;
    if (idx < C4) v[k] = row4[idx];
    else          v[k] = make_float4(-FLT_MAX, -FLT_MAX, -FLT_MAX, -FLT_MAX);
  }
  float m1 = -FLT_MAX, m2 = -FLT_MAX;
  int   i1 = 0x7fffffff;
#pragma unroll
  for (int k = 0; k < NK; ++k) {
    int base = 4 * (lane + 64 * k);
    float a0 = v[k].x, a1 = v[k].y, a2 = v[k].z, a3 = v[k].w;
    if (a0 > m1) { m2 = m1; m1 = a0; i1 = base;     } else if (a0 > m2) m2 = a0;
    if (a1 > m1) { m2 = m1; m1 = a1; i1 = base + 1; } else if (a1 > m2) m2 = a1;
    if (a2 > m1) { m2 = m1; m1 = a2; i1 = base + 2; } else if (a2 > m2) m2 = a2;
    if (a3 > m1) { m2 = m1; m1 = a3; i1 = base + 3; } else if (a3 > m2) m2 = a3;
  }
  float Z = 0.f;
#pragma unroll
  for (int k = 0; k < NK; ++k) {
    Z += __expf(v[k].x - m1);   // sentinel lanes: exp(-huge) = 0
    Z += __expf(v[k].y - m1);
    Z += __expf(v[k].z - m1);
    Z += __expf(v[k].w - m1);
  }
  // Butterfly reduce across the 64-lane wave (all lanes converge to the result).
#pragma unroll
  for (int off = 32; off > 0; off >>= 1) {
    float bm1 = __shfl_xor(m1, off);
    int   bi1 = __shfl_xor(i1, off);
    float bm2 = __shfl_xor(m2, off);
    float bZ  = __shfl_xor(Z,  off);
    combine_stats(m1, i1, m2, Z, bm1, bi1, bm2, bZ);
  }
  float invZ = 1.0f / Z;
  float xt   = row[target];       // same addr across wave -> one broadcast load (L1/L2 hit)
  p_top1 = invZ;                  // exp(m1-m1)/Z
  p_top2 = __expf(m2 - m1) * invZ;
  p_tgt  = __expf(xt - m1) * invZ;
  amax   = i1;
}

template<bool ATOMIC>
__global__ __launch_bounds__(256) void rank_loss_kernel(
    const float* __restrict__ s, const float* __restrict__ r, const float* __restrict__ o,
    const int* __restrict__ st, const int* __restrict__ rt, const int* __restrict__ ot,
    float* __restrict__ partial, float* __restrict__ out) {
  const int wid  = threadIdx.x >> 6;
  const int lane = threadIdx.x & 63;
  const int row  = blockIdx.x * 4 + wid;   // grid = B/4 exactly

  const float* srow = s + (size_t)row * C_ENT;
  const float* rrow = r + (size_t)row * C_REL;
  const float* orow = o + (size_t)row * C_ENT;
  const int tS = st[row], tR = rt[row], tO = ot[row];

  float sp0, sp1, spt; int sa;
  float rp0, rp1, rpt; int ra;
  float op0, op1, opt; int oa;
  row_stats<4, C_ENT / 4>(srow, lane, tS, sp0, sp1, sa, spt);
  row_stats<2, C_REL / 4>(rrow, lane, tR, rp0, rp1, ra, rpt);
  row_stats<4, C_ENT / 4>(orow, lane, tO, op0, op1, oa, opt);

  if (lane == 0) {
    float gt   = spt * rpt * opt;
    float top1 = sp0 * rp0 * op0;
    // second-smallest of the 8 top2-products = min of the three one-swap products
    float c1 = sp0 * rp1 * op1;
    float c2 = sp1 * rp0 * op1;
    float c3 = sp1 * rp1 * op0;
    float second = fminf(c1, fminf(c2, c3));
    bool cond = (sa == tS) && (ra == tR) && (oa == tO);
    float pre = cond ? second : top1;
    float val = fmaxf(1.0f - gt + pre, 0.0f);
    if (ATOMIC) atomicAdd(out, val * (1.0f / (float)B));
    else        partial[row] = val;
  }
}

__global__ __launch_bounds__(1024) void reduce_sum_kernel(const float* __restrict__ p,
                                                          float* __restrict__ out) {
  const float4* p4 = (const float4*)p;
  float sum = 0.f;
  for (int i = threadIdx.x; i < B / 4; i += 1024) {
    float4 v = p4[i];
    sum += (v.x + v.y) + (v.z + v.w);
  }
#pragma unroll
  for (int off = 32; off > 0; off >>= 1) sum += __shfl_xor(sum, off);
  __shared__ float lds[16];
  if ((threadIdx.x & 63) == 0) lds[threadIdx.x >> 6] = sum;
  __syncthreads();
  if (threadIdx.x == 0) {
    float t = 0.f;
#pragma unroll
    for (int i = 0; i < 16; ++i) t += lds[i];
    out[0] = t * (1.0f / (float)B);
  }
}

extern "C" void kernel_launch(void* const* d_in, const int* in_sizes, int n_in,
                              void* d_out, int out_size, void* d_ws, size_t ws_size,
                              hipStream_t stream) {
  const float* s  = (const float*)d_in[0];
  const float* r  = (const float*)d_in[1];
  const float* o  = (const float*)d_in[2];
  const int*   st = (const int*)d_in[3];
  const int*   rt = (const int*)d_in[4];
  const int*   ot = (const int*)d_in[5];
  float* out = (float*)d_out;

  if (ws_size >= (size_t)B * sizeof(float)) {
    float* partial = (float*)d_ws;
    rank_loss_kernel<false><<<B / 4, 256, 0, stream>>>(s, r, o, st, rt, ot, partial, nullptr);
    reduce_sum_kernel<<<1, 1024, 0, stream>>>(partial, out);
  } else {
    // fallback: atomic accumulation (d_out is poisoned 0xAA -> zero it first)
    hipMemsetAsync(d_out, 0, sizeof(float), stream);
    rank_loss_kernel<true><<<B / 4, 256, 0, stream>>>(s, r, o, st, rt, ot, nullptr, out);
  }
}

// Round 2
// 319.410 us; speedup vs baseline: 1.0039x; 1.0039x over previous
//
#include <hip/hip_runtime.h>
#include <float.h>
#include <limits.h>

// RankLoss round 2: one wave per (row, matrix) -> 98304 waves, 1/3 the serial
// chain per wave vs round 1, all loads issued upfront (max MLP).
// Per-wave stats: tree max -> 1-float butterfly (m1); independent exps;
// eq-based argmax/m2/cnt trees; one combined (Z,m2,cnt,idx) butterfly.
// Stats (float4) -> d_ws; combine kernel -> per-row loss; reduce -> mean.

constexpr int B      = 32768;
constexpr int C_ENT  = 1000;   // 250 float4
constexpr int C_REL  = 500;    // 125 float4

// ---------------- round-2 path: per-(row,matrix) wave stats ----------------

template<int NK, int C4>
__device__ inline float4 wave_stats(const float* __restrict__ row, int lane, int target) {
  const float4* row4 = (const float4*)row;
  float4 v[NK];
#pragma unroll
  for (int k = 0; k < NK; ++k) {
    int i = lane + 64 * k;
    v[k] = (i < C4) ? row4[i] : make_float4(-FLT_MAX, -FLT_MAX, -FLT_MAX, -FLT_MAX);
  }
  float xt = row[target];   // broadcast load, issued with the vector loads

  // ---- m1: local max tree, then 1-float butterfly ----
  float lm = -FLT_MAX;
#pragma unroll
  for (int k = 0; k < NK; ++k)
    lm = fmaxf(lm, fmaxf(fmaxf(v[k].x, v[k].y), fmaxf(v[k].z, v[k].w)));
#pragma unroll
  for (int off = 32; off; off >>= 1)
    lm = fmaxf(lm, __shfl_xor(lm, off));
  const float m1 = lm;

  // ---- independent exps + eq-based (m2, argmax, dup-count) trees ----
  float z[NK];
  float m2 = -FLT_MAX;
  int   idx = INT_MAX;
  int   cnt = 0;
#pragma unroll
  for (int k = 0; k < NK; ++k) {
    const int base = 4 * (lane + 64 * k);
    const float a0 = v[k].x, a1 = v[k].y, a2 = v[k].z, a3 = v[k].w;
    // sentinel lanes: a - m1 = -inf/-huge -> __expf = 0, no NaN (m1 finite)
    z[k] = (__expf(a0 - m1) + __expf(a1 - m1)) + (__expf(a2 - m1) + __expf(a3 - m1));
    const bool e0 = (a0 == m1), e1 = (a1 == m1), e2 = (a2 == m1), e3 = (a3 == m1);
    cnt += (int)e0 + (int)e1 + (int)e2 + (int)e3;
    m2 = fmaxf(m2, fmaxf(e0 ? -FLT_MAX : a0, e1 ? -FLT_MAX : a1));
    m2 = fmaxf(m2, fmaxf(e2 ? -FLT_MAX : a2, e3 ? -FLT_MAX : a3));
    const int i01 = min(e0 ? base     : INT_MAX, e1 ? base + 1 : INT_MAX);
    const int i23 = min(e2 ? base + 2 : INT_MAX, e3 ? base + 3 : INT_MAX);
    idx = min(idx, min(i01, i23));
  }
  float Z;
  if constexpr (NK == 4) Z = (z[0] + z[1]) + (z[2] + z[3]);
  else                   Z = z[0] + z[1];

  // ---- combined butterfly: Z sum, m2 max, cnt sum, idx min ----
#pragma unroll
  for (int off = 32; off; off >>= 1) {
    Z   += __shfl_xor(Z, off);
    m2   = fmaxf(m2, __shfl_xor(m2, off));
    cnt += __shfl_xor(cnt, off);
    idx  = min(idx, __shfl_xor(idx, off));
  }
  if (cnt >= 2) m2 = m1;   // max value duplicated -> true second max == max

  const float invZ = 1.0f / Z;
  return make_float4(invZ,                     // p_top1 = exp(m1-m1)/Z
                     __expf(m2 - m1) * invZ,   // p_top2
                     __expf(xt - m1) * invZ,   // p_target
                     __int_as_float(idx));     // argmax (lowest index on tie)
}

__global__ __launch_bounds__(256) void stats_kernel(
    const float* __restrict__ s, const float* __restrict__ r, const float* __restrict__ o,
    const int* __restrict__ st, const int* __restrict__ rt, const int* __restrict__ ot,
    float4* __restrict__ out4) {
  const int wid  = threadIdx.x >> 6;
  const int lane = threadIdx.x & 63;
  const int gw   = blockIdx.x * 4 + wid;   // grid = 3*B/4 -> gw in [0, 3B)
  const int m    = gw >> 15;               // 0: s, 1: o, 2: r (wave-uniform)
  const int row  = gw & (B - 1);
  float4 res;
  if (m == 0)      res = wave_stats<4, C_ENT / 4>(s + (size_t)row * C_ENT, lane, st[row]);
  else if (m == 1) res = wave_stats<4, C_ENT / 4>(o + (size_t)row * C_ENT, lane, ot[row]);
  else             res = wave_stats<2, C_REL / 4>(r + (size_t)row * C_REL, lane, rt[row]);
  if (lane == 0) out4[m * B + row] = res;
}

__global__ __launch_bounds__(256) void combine_kernel(
    const float4* __restrict__ stat4,
    const int* __restrict__ st, const int* __restrict__ rt, const int* __restrict__ ot,
    float* __restrict__ partial) {
  const int row = blockIdx.x * 256 + threadIdx.x;   // grid = B/256
  const float4 S = stat4[row];           // m=0
  const float4 O = stat4[B + row];       // m=1
  const float4 R = stat4[2 * B + row];   // m=2
  const float gt   = S.z * R.z * O.z;
  const float top1 = S.x * R.x * O.x;
  // second-smallest of the 8 top2-products = min of the three one-swap products
  const float c1 = S.x * R.y * O.y;
  const float c2 = S.y * R.x * O.y;
  const float c3 = S.y * R.y * O.x;
  const float second = fminf(c1, fminf(c2, c3));
  const bool cond = (__float_as_int(S.w) == st[row]) &&
                    (__float_as_int(R.w) == rt[row]) &&
                    (__float_as_int(O.w) == ot[row]);
  const float pre = cond ? second : top1;
  partial[row] = fmaxf(1.0f - gt + pre, 0.0f);
}

// ---------------- round-1 fallback: one wave per row ----------------

__device__ inline void combine_stats(float& m1, int& i1, float& m2, float& Z,
                                     float bm1, int bi1, float bm2, float bZ) {
  bool bwin = (bm1 > m1) || (bm1 == m1 && bi1 < i1);
  float wm1 = bwin ? bm1 : m1;
  int   wi1 = bwin ? bi1 : i1;
  float wm2 = bwin ? bm2 : m2;
  float lm1 = bwin ? m1  : bm1;
  float wZ  = bwin ? bZ  : Z;
  float lZ  = bwin ? Z   : bZ;
  m1 = wm1; i1 = wi1;
  m2 = fmaxf(wm2, lm1);
  Z  = wZ + lZ * __expf(lm1 - wm1);
}

template<int NK, int C4>
__device__ inline void row_stats(const float* __restrict__ row, int lane, int target,
                                 float& p_top1, float& p_top2, int& amax, float& p_tgt) {
  const float4* row4 = (const float4*)row;
  float4 v[NK];
#pragma unroll
  for (int k = 0; k < NK; ++k) {
    int idx = lane + 64 * k;
    v[k] = (idx < C4) ? row4[idx] : make_float4(-FLT_MAX, -FLT_MAX, -FLT_MAX, -FLT_MAX);
  }
  float m1 = -FLT_MAX, m2 = -FLT_MAX;
  int   i1 = 0x7fffffff;
#pragma unroll
  for (int k = 0; k < NK; ++k) {
    int base = 4 * (lane + 64 * k);
    float a0 = v[k].x, a1 = v[k].y, a2 = v[k].z, a3 = v[k].w;
    if (a0 > m1) { m2 = m1; m1 = a0; i1 = base;     } else if (a0 > m2) m2 = a0;
    if (a1 > m1) { m2 = m1; m1 = a1; i1 = base + 1; } else if (a1 > m2) m2 = a1;
    if (a2 > m1) { m2 = m1; m1 = a2; i1 = base + 2; } else if (a2 > m2) m2 = a2;
    if (a3 > m1) { m2 = m1; m1 = a3; i1 = base + 3; } else if (a3 > m2) m2 = a3;
  }
  float Z = 0.f;
#pragma unroll
  for (int k = 0; k < NK; ++k) {
    Z += __expf(v[k].x - m1); Z += __expf(v[k].y - m1);
    Z += __expf(v[k].z - m1); Z += __expf(v[k].w - m1);
  }
#pragma unroll
  for (int off = 32; off > 0; off >>= 1) {
    float bm1 = __shfl_xor(m1, off);
    int   bi1 = __shfl_xor(i1, off);
    float bm2 = __shfl_xor(m2, off);
    float bZ  = __shfl_xor(Z,  off);
    combine_stats(m1, i1, m2, Z, bm1, bi1, bm2, bZ);
  }
  float invZ = 1.0f / Z;
  float xt   = row[target];
  p_top1 = invZ;
  p_top2 = __expf(m2 - m1) * invZ;
  p_tgt  = __expf(xt - m1) * invZ;
  amax   = i1;
}

template<bool ATOMIC>
__global__ __launch_bounds__(256) void rank_loss_kernel(
    const float* __restrict__ s, const float* __restrict__ r, const float* __restrict__ o,
    const int* __restrict__ st, const int* __restrict__ rt, const int* __restrict__ ot,
    float* __restrict__ partial, float* __restrict__ out) {
  const int wid  = threadIdx.x >> 6;
  const int lane = threadIdx.x & 63;
  const int row  = blockIdx.x * 4 + wid;

  const float* srow = s + (size_t)row * C_ENT;
  const float* rrow = r + (size_t)row * C_REL;
  const float* orow = o + (size_t)row * C_ENT;
  const int tS = st[row], tR = rt[row], tO = ot[row];

  float sp0, sp1, spt; int sa;
  float rp0, rp1, rpt; int ra;
  float op0, op1, opt; int oa;
  row_stats<4, C_ENT / 4>(srow, lane, tS, sp0, sp1, sa, spt);
  row_stats<2, C_REL / 4>(rrow, lane, tR, rp0, rp1, ra, rpt);
  row_stats<4, C_ENT / 4>(orow, lane, tO, op0, op1, oa, opt);

  if (lane == 0) {
    float gt   = spt * rpt * opt;
    float top1 = sp0 * rp0 * op0;
    float c1 = sp0 * rp1 * op1;
    float c2 = sp1 * rp0 * op1;
    float c3 = sp1 * rp1 * op0;
    float second = fminf(c1, fminf(c2, c3));
    bool cond = (sa == tS) && (ra == tR) && (oa == tO);
    float pre = cond ? second : top1;
    float val = fmaxf(1.0f - gt + pre, 0.0f);
    if (ATOMIC) atomicAdd(out, val * (1.0f / (float)B));
    else        partial[row] = val;
  }
}

// ---------------- final mean reduction ----------------

__global__ __launch_bounds__(1024) void reduce_sum_kernel(const float* __restrict__ p,
                                                          float* __restrict__ out) {
  const float4* p4 = (const float4*)p;
  float sum = 0.f;
  for (int i = threadIdx.x; i < B / 4; i += 1024) {
    float4 v = p4[i];
    sum += (v.x + v.y) + (v.z + v.w);
  }
#pragma unroll
  for (int off = 32; off > 0; off >>= 1) sum += __shfl_xor(sum, off);
  __shared__ float lds[16];
  if ((threadIdx.x & 63) == 0) lds[threadIdx.x >> 6] = sum;
  __syncthreads();
  if (threadIdx.x == 0) {
    float t = 0.f;
#pragma unroll
    for (int i = 0; i < 16; ++i) t += lds[i];
    out[0] = t * (1.0f / (float)B);
  }
}

extern "C" void kernel_launch(void* const* d_in, const int* in_sizes, int n_in,
                              void* d_out, int out_size, void* d_ws, size_t ws_size,
                              hipStream_t stream) {
  const float* s  = (const float*)d_in[0];
  const float* r  = (const float*)d_in[1];
  const float* o  = (const float*)d_in[2];
  const int*   st = (const int*)d_in[3];
  const int*   rt = (const int*)d_in[4];
  const int*   ot = (const int*)d_in[5];
  float* out = (float*)d_out;

  const size_t statBytes = (size_t)3 * B * sizeof(float4);          // 1.5 MiB
  if (ws_size >= statBytes + (size_t)B * sizeof(float)) {
    float4* stat4  = (float4*)d_ws;
    float* partial = (float*)((char*)d_ws + statBytes);
    stats_kernel<<<3 * B / 4, 256, 0, stream>>>(s, r, o, st, rt, ot, stat4);
    combine_kernel<<<B / 256, 256, 0, stream>>>(stat4, st, rt, ot, partial);
    reduce_sum_kernel<<<1, 1024, 0, stream>>>(partial, out);
  } else if (ws_size >= (size_t)B * sizeof(float)) {
    float* partial = (float*)d_ws;
    rank_loss_kernel<false><<<B / 4, 256, 0, stream>>>(s, r, o, st, rt, ot, partial, nullptr);
    reduce_sum_kernel<<<1, 1024, 0, stream>>>(partial, out);
  } else {
    hipMemsetAsync(d_out, 0, sizeof(float), stream);
    rank_loss_kernel<true><<<B / 4, 256, 0, stream>>>(s, r, o, st, rt, ot, nullptr, out);
  }
}